// Round 5
// baseline (44.610 us; speedup 1.0000x reference)
//
#include <hip/hip_runtime.h>
#include <math.h>

#define BATCH 8192
#define NLEN 4096

// ---------------------------------------------------------------------------
// Kernel 1: ONE WAVE PER ROW (4 rows per 256-thread block).
// COALESCED + BRANCHLESS + PARALLEL FIXUPS.
//   - 16 loads per wave; load g: lane l reads float4 at element g*256+l*4
//     -> every load is a perfect 64x16B = 1 KiB coalesced transaction.
//     All 16 issued upfront (16 KiB/wave in flight).
//   - Element order (g, lane, k): intra-lane diffs branchless over k (zeros
//     contribute 0 to sum/sumsq -> no mask needed there).
//   - Per-load cross-lane boundary: ballot + nearest-lower-valid-lane
//     bpermute (independent per g, NO serial carry).
//   - Per-load wave-uniform first/last/has saved; the 16 load-boundary
//     diffs are stitched in a final unrolled uniform pass (pure VALU),
//     added ONCE after the butterfly reduction.
// ---------------------------------------------------------------------------
__global__ __launch_bounds__(256) void hrv_feats_kernel(
    const float* __restrict__ rr, float* __restrict__ feats) {
    const int lane = threadIdx.x & 63;
    const int wid = threadIdx.x >> 6;
    const int row = blockIdx.x * 4 + wid;
    const float* rbase = rr + (size_t)row * NLEN + lane * 4;

    float4 v4[16];
#pragma unroll
    for (int g = 0; g < 16; ++g)
        v4[g] = *reinterpret_cast<const float4*>(rbase + g * 256);

    double dsum = 0.0, dsumsq = 0.0, dsumd2 = 0.0;
    int cnt = 0, nn50 = 0;
    float fg[16], lg[16];      // wave-uniform first/last valid of load g
    unsigned int hasbits = 0;  // bit g = load g has any valid element

    float s = 0.f, s2 = 0.f, d2 = 0.f;  // f32 partials, folded every 4 loads
#pragma unroll
    for (int g = 0; g < 16; ++g) {
        const float xx[4] = {v4[g].x, v4[g].y, v4[g].z, v4[g].w};
        float prev = 0.f, first = 0.f;
        bool has = false;
#pragma unroll
        for (int k = 0; k < 4; ++k) {
            const float v = xx[k];
            const bool val = v > 0.f;
            s += v;  // padding is exactly 0 -> unmasked
            s2 = fmaf(v, v, s2);
            cnt += val ? 1 : 0;
            const float d = v - prev;  // same f32 sub as reference
            const float dm = (val && has) ? d : 0.f;
            d2 = fmaf(dm, dm, d2);
            nn50 += (fabsf(dm) > 0.05f) ? 1 : 0;
            first = (val && !has) ? v : first;
            prev = val ? v : prev;
            has = has || val;
        }
        // cross-lane boundary within load g (independent across g)
        const unsigned long long m = __ballot(has);
        const unsigned long long pm = m & ((1ull << lane) - 1ull);
        const int j = 63 - __clzll(pm | 1ull);
        const float lastj = __shfl(prev, j, 64);
        const float dB = first - lastj;
        const float dBm = (has && pm) ? dB : 0.f;
        d2 = fmaf(dBm, dBm, d2);
        nn50 += (fabsf(dBm) > 0.05f) ? 1 : 0;
        // wave-uniform per-load first/last (for the stitch pass)
        const int hi = 63 - __clzll(m | 1ull);
        const int lo = (m != 0ull) ? (__ffsll((unsigned long long)m) - 1) : 0;
        lg[g] = __shfl(prev, hi, 64);
        fg[g] = __shfl(first, lo, 64);
        hasbits |= (m != 0ull) ? (1u << g) : 0u;

        if ((g & 3) == 3) {  // fold f32 partials (16 elems) into doubles
            dsum += s; dsumsq += s2; dsumd2 += d2;
            s = 0.f; s2 = 0.f; d2 = 0.f;
        }
    }

    // stitch the 16 load boundaries: all values wave-uniform, pure VALU
    float run_last = 0.f, sd2 = 0.f;
    int run_has = 0, snn = 0;
#pragma unroll
    for (int g = 0; g < 16; ++g) {
        const int hg = (hasbits >> g) & 1;
        const float d = fg[g] - run_last;
        const float dm = (hg && run_has) ? d : 0.f;
        sd2 = fmaf(dm, dm, sd2);
        snn += (fabsf(dm) > 0.05f) ? 1 : 0;
        run_last = hg ? lg[g] : run_last;
        run_has |= hg;
    }

    // xor-butterfly reduction: ALL lanes end with totals
#pragma unroll
    for (int off = 32; off; off >>= 1) {
        dsum += __shfl_xor(dsum, off, 64);
        dsumsq += __shfl_xor(dsumsq, off, 64);
        dsumd2 += __shfl_xor(dsumd2, off, 64);
        cnt += __shfl_xor(cnt, off, 64);
        nn50 += __shfl_xor(nn50, off, 64);
    }
    // add the (uniform) stitch terms ONCE, post-reduction
    dsumd2 += (double)sd2;
    nn50 += snn;

    const float cntf = (float)cnt;
    const float denom_m = fmaxf(cntf, 1.f);
    const float mean = (float)(dsum / (double)denom_m);
    const float varsum = (float)(dsumsq - (double)cnt * (double)mean * (double)mean);
    const float denom_v = fmaxf(cntf - 1.f, 1.f);
    const float sdnn = sqrtf(fmaxf(varsum / denom_v, 0.f));
    const float rmssd = sqrtf(fmaxf((float)(dsumd2 / (double)denom_v), 0.f));
    const float pnn50 = (float)nn50 / denom_v;
    const float hr = 60.f / fmaxf(mean, 1e-12f);
    const float cv = sdnn / fmaxf(mean, 1e-12f);

    float val = mean;  // lane 0
    val = (lane == 1) ? sdnn : val;
    val = (lane == 2) ? rmssd : val;
    val = (lane == 3) ? pnn50 : val;
    val = (lane == 4) ? hr : val;
    val = (lane == 5) ? cv : val;
    if (cnt <= 1) val = 0.f;
    // COLUMN-MAJOR: feats[c][row] -> coalesced reads in kernel 2
    if (lane < 6) feats[lane * BATCH + row] = val;
}

// ---------------------------------------------------------------------------
// Kernel 2 (fused col-stats + MLP): 32 blocks x 256 threads. Each block
// redundantly computes column mean/std(ddof=1)/max over the column-major
// feats (float4-coalesced, L2/L3-resident, f64 accum for the catastrophic
// (sumsq - B*mean^2) cancellation), then applies normalize + 6->16 ReLU ->
// 32 MLP to its own 256 rows. Deterministic identical stats per block.
// ---------------------------------------------------------------------------
__global__ __launch_bounds__(256) void stats_mlp_kernel(
    const float* __restrict__ feats,
    const float* __restrict__ w1, const float* __restrict__ b1,
    const float* __restrict__ w2, const float* __restrict__ b2,
    float* __restrict__ out) {
    __shared__ double sh_s[4][6], sh_s2[4][6];
    __shared__ float sh_m[4][6];
    __shared__ float sh_stats[18];  // mean[6], std[6], max[6]

    const int t = threadIdx.x;
    double s[6], s2[6];
    float mx[6];
#pragma unroll
    for (int c = 0; c < 6; ++c) { s[c] = 0.0; s2[c] = 0.0; mx[c] = -INFINITY; }

#pragma unroll
    for (int c = 0; c < 6; ++c) {
        const float4* col = reinterpret_cast<const float4*>(feats + c * BATCH);
#pragma unroll
        for (int it = 0; it < BATCH / 4 / 256; ++it) {  // 8 iters
            float4 f4 = col[t + it * 256];
            const float f[4] = {f4.x, f4.y, f4.z, f4.w};
#pragma unroll
            for (int k = 0; k < 4; ++k) {
                s[c] += (double)f[k];
                s2[c] += (double)f[k] * (double)f[k];
                mx[c] = fmaxf(mx[c], f[k]);
            }
        }
    }
#pragma unroll
    for (int off = 32; off; off >>= 1) {
#pragma unroll
        for (int c = 0; c < 6; ++c) {
            s[c] += __shfl_down(s[c], off, 64);
            s2[c] += __shfl_down(s2[c], off, 64);
            mx[c] = fmaxf(mx[c], __shfl_down(mx[c], off, 64));
        }
    }
    if ((t & 63) == 0) {
        const int w = t >> 6;
#pragma unroll
        for (int c = 0; c < 6; ++c) {
            sh_s[w][c] = s[c];
            sh_s2[w][c] = s2[c];
            sh_m[w][c] = mx[c];
        }
    }
    __syncthreads();
    if (t < 6) {
        double S = 0, S2 = 0;
        float M = -INFINITY;
        for (int w = 0; w < 4; ++w) {
            S += sh_s[w][t];
            S2 += sh_s2[w][t];
            M = fmaxf(M, sh_m[w][t]);
        }
        const double meanb = S / (double)BATCH;
        double var = (S2 - (double)BATCH * meanb * meanb) / (double)(BATCH - 1);
        if (var < 0.0) var = 0.0;
        sh_stats[t] = (float)meanb;
        sh_stats[6 + t] = (float)sqrt(var);
        sh_stats[12 + t] = M;
    }
    __syncthreads();

    const int row = blockIdx.x * 256 + t;
    float f[6];
#pragma unroll
    for (int c = 0; c < 6; ++c) {
        float v = feats[c * BATCH + row];  // coalesced across threads
        if (sh_stats[12 + c] > 0.f) v = (v - sh_stats[c]) / (sh_stats[6 + c] + 1e-8f);
        f[c] = v;
    }
    float h[16];
#pragma unroll
    for (int j = 0; j < 16; ++j) {
        float a = b1[j];
#pragma unroll
        for (int c = 0; c < 6; ++c) a = fmaf(f[c], w1[c * 16 + j], a);
        h[j] = fmaxf(a, 0.f);
    }
    float o[32];
#pragma unroll
    for (int k = 0; k < 32; ++k) o[k] = b2[k];
#pragma unroll
    for (int j = 0; j < 16; ++j) {
        const float hj = h[j];
#pragma unroll
        for (int k = 0; k < 32; ++k) o[k] = fmaf(hj, w2[j * 32 + k], o[k]);
    }
    float4* ov = reinterpret_cast<float4*>(out + (size_t)row * 32);
    const float4* op = reinterpret_cast<const float4*>(o);
#pragma unroll
    for (int i = 0; i < 8; ++i) ov[i] = op[i];
}

extern "C" void kernel_launch(void* const* d_in, const int* in_sizes, int n_in,
                              void* d_out, int out_size, void* d_ws, size_t ws_size,
                              hipStream_t stream) {
    const float* rr = (const float*)d_in[0];
    const float* w1 = (const float*)d_in[1];
    const float* b1 = (const float*)d_in[2];
    const float* w2 = (const float*)d_in[3];
    const float* b2 = (const float*)d_in[4];
    float* out = (float*)d_out;
    float* feats = (float*)d_ws;  // column-major [6][BATCH] = 192 KiB

    hrv_feats_kernel<<<BATCH / 4, 256, 0, stream>>>(rr, feats);
    stats_mlp_kernel<<<BATCH / 256, 256, 0, stream>>>(feats, w1, b1, w2, b2, out);
}